// Round 1
// baseline (40.086 us; speedup 1.0000x reference)
//
#include <hip/hip_runtime.h>
#include <hip/hip_bf16.h>

// Fast exp2 -> single v_exp_f32
#if defined(__has_builtin)
#if __has_builtin(__builtin_amdgcn_exp2f)
#define FAST_EXP2(x) __builtin_amdgcn_exp2f(x)
#endif
#endif
#ifndef FAST_EXP2
#define FAST_EXP2(x) exp2f(x)
#endif

#define N_TRAIN 8192
#define BSZ 4096
#define NOUT (BSZ * 3)   // 12288
#define BLK 256

// ---------------------------------------------------------------------------
// prep: per train point n: A_d = c*z_d^2, B_d = -2*c*z_d (z = W @ train_X[n]),
//       packed as AY[n] = (A0,A1,A2, Y[n]), B4[n] = (B0,B1,B2, 0).
//       per batch point b: XW[b] = (xw0, xw1, xw2, 0), xw = W @ x[b].
// c = -log2(e) / (2 h^2).  The dropped exp2(c*xw^2) factor cancels in the
// numerator/denominator ratio.
// ---------------------------------------------------------------------------
__global__ __launch_bounds__(BLK) void prep_k(
    const float4* __restrict__ x4,    // [4096] rows of x
    const float4* __restrict__ tX4,   // [8192] rows of train_X
    const float*  __restrict__ Y,     // [8192]
    const float*  __restrict__ W,     // [3][4]
    const float*  __restrict__ hptr,  // [1]
    float4* __restrict__ AY,
    float4* __restrict__ B4,
    float4* __restrict__ XW)
{
    int idx = blockIdx.x * BLK + threadIdx.x;
    float h = hptr[0];
    float c = -0.72134752044448170368f / (h * h);  // -log2(e)/2 / h^2

    const float4* Wv = (const float4*)W;
    float4 w0 = Wv[0], w1 = Wv[1], w2 = Wv[2];

    if (idx < N_TRAIN) {
        float4 t = tX4[idx];
        float z0 = t.x * w0.x + t.y * w0.y + t.z * w0.z + t.w * w0.w;
        float z1 = t.x * w1.x + t.y * w1.y + t.z * w1.z + t.w * w1.w;
        float z2 = t.x * w2.x + t.y * w2.y + t.z * w2.z + t.w * w2.w;
        AY[idx] = make_float4(c * z0 * z0, c * z1 * z1, c * z2 * z2, Y[idx]);
        B4[idx] = make_float4(-2.f * c * z0, -2.f * c * z1, -2.f * c * z2, 0.f);
    } else {
        int b = idx - N_TRAIN;  // < 4096
        float4 t = x4[b];
        float x0 = t.x * w0.x + t.y * w0.y + t.z * w0.z + t.w * w0.w;
        float x1 = t.x * w1.x + t.y * w1.y + t.z * w1.z + t.w * w1.w;
        float x2 = t.x * w2.x + t.y * w2.y + t.z * w2.z + t.w * w2.w;
        XW[b] = make_float4(x0, x1, x2, 0.f);
    }
}

// ---------------------------------------------------------------------------
// main: block = 256 threads = 256 consecutive b's; blockIdx -> (b-block, seg).
// Each block loops over its n-segment in 256-point LDS tiles; every thread
// reads the same LDS address per iteration (broadcast, conflict-free).
// Per (n,d) term: 1 fma + 1 v_exp_f32 + 1 add + 1 fma.
// ---------------------------------------------------------------------------
__global__ __launch_bounds__(BLK) void kde_k(
    const float4* __restrict__ AY,
    const float4* __restrict__ B4,
    const float4* __restrict__ XW,
    float* __restrict__ NP,   // [ns][12288] numerator partials
    float* __restrict__ DP,   // [ns][12288] denominator partials
    int nb)                   // train points per segment (multiple of 256)
{
    __shared__ float4 sA[256];
    __shared__ float4 sB[256];

    int tid  = threadIdx.x;
    int bblk = blockIdx.x & 15;   // 16 b-blocks
    int seg  = blockIdx.x >> 4;
    int n0   = seg * nb;
    int b    = (bblk << 8) + tid;

    float4 xw = XW[b];
    float num0 = 0.f, num1 = 0.f, num2 = 0.f;
    float den0 = 0.f, den1 = 0.f, den2 = 0.f;

    for (int t0 = 0; t0 < nb; t0 += 256) {
        sA[tid] = AY[n0 + t0 + tid];
        sB[tid] = B4[n0 + t0 + tid];
        __syncthreads();

        #pragma unroll 8
        for (int i = 0; i < 256; ++i) {
            float4 a  = sA[i];
            float4 bb = sB[i];
            float e0 = FAST_EXP2(fmaf(bb.x, xw.x, a.x));
            float e1 = FAST_EXP2(fmaf(bb.y, xw.y, a.y));
            float e2 = FAST_EXP2(fmaf(bb.z, xw.z, a.z));
            den0 += e0;
            den1 += e1;
            den2 += e2;
            num0 = fmaf(e0, a.w, num0);
            num1 = fmaf(e1, a.w, num1);
            num2 = fmaf(e2, a.w, num2);
        }
        __syncthreads();
    }

    int base = seg * NOUT + b * 3;
    NP[base + 0] = num0;
    NP[base + 1] = num1;
    NP[base + 2] = num2;
    DP[base + 0] = den0;
    DP[base + 1] = den1;
    DP[base + 2] = den2;
}

// ---------------------------------------------------------------------------
// reduce: one thread per output element, sum ns partials, divide.
// ---------------------------------------------------------------------------
__global__ __launch_bounds__(BLK) void reduce_k(
    const float* __restrict__ NP,
    const float* __restrict__ DP,
    float* __restrict__ out,
    int ns)
{
    int t = blockIdx.x * BLK + threadIdx.x;  // < 12288
    float n = 0.f, d = 0.f;
    for (int s = 0; s < ns; ++s) {
        n += NP[s * NOUT + t];
        d += DP[s * NOUT + t];
    }
    out[t] = n / d;
}

extern "C" void kernel_launch(void* const* d_in, const int* in_sizes, int n_in,
                              void* d_out, int out_size, void* d_ws, size_t ws_size,
                              hipStream_t stream) {
    const float* x   = (const float*)d_in[0];  // [4096,4]
    const float* tX  = (const float*)d_in[1];  // [8192,4]
    const float* Y   = (const float*)d_in[2];  // [8192]
    const float* W   = (const float*)d_in[3];  // [3,4]
    const float* h   = (const float*)d_in[4];  // [1]
    float* out = (float*)d_out;                // [4096,3]

    // ws layout (floats):
    //   AY  : 8192 float4
    //   B4  : 8192 float4
    //   XW  : 4096 float4
    //   NP  : ns * 12288 floats
    //   DP  : ns * 12288 floats
    float4* AY = (float4*)d_ws;
    float4* B4 = AY + N_TRAIN;
    float4* XW = B4 + N_TRAIN;
    float*  NP = (float*)(XW + BSZ);

    size_t fixed_bytes = (size_t)(2 * N_TRAIN + BSZ) * sizeof(float4);
    int ns = 32;  // n-segments; partials = ns * 12288 * 2 * 4 B
    while (ns > 1 &&
           fixed_bytes + (size_t)ns * NOUT * 2 * sizeof(float) > ws_size) {
        ns >>= 1;
    }
    float* DP = NP + (size_t)ns * NOUT;
    int nb = N_TRAIN / ns;  // multiple of 256 for ns <= 32

    prep_k<<<(N_TRAIN + BSZ) / BLK, BLK, 0, stream>>>(
        (const float4*)x, (const float4*)tX, Y, W, h, AY, B4, XW);

    kde_k<<<16 * ns, BLK, 0, stream>>>(AY, B4, XW, NP, DP, nb);

    reduce_k<<<NOUT / BLK, BLK, 0, stream>>>(NP, DP, out, ns);
}